// Round 15
// baseline (791.480 us; speedup 1.0000x reference)
//
#include <hip/hip_runtime.h>
#include <stdint.h>
#include <math.h>

typedef uint32_t u32;
typedef uint64_t u64;
typedef unsigned short u16;

#define B_T    16384
#define DD     512
#define NE     64
#define KCAP   512
#define TWO_D  1024

typedef __attribute__((ext_vector_type(8))) short bf16x8;
typedef __attribute__((ext_vector_type(4))) float f32x4;

static __device__ __forceinline__ u32 mono_of(float s) {
  u32 b = __float_as_uint(s);
  return (b & 0x80000000u) ? ~b : (b | 0x80000000u);
}
static __device__ __forceinline__ float score_from_mono(u32 m) {
  u32 b = (m & 0x80000000u) ? (m ^ 0x80000000u) : ~m;
  return __uint_as_float(b);
}
static __device__ __forceinline__ u16 f2bf(float f) {
  u32 b = __float_as_uint(f);
  b += 0x7FFFu + ((b >> 16) & 1u);
  return (u16)(b >> 16);
}
static __device__ __forceinline__ u32 f2bf2(float lo, float hi) {
  return (u32)f2bf(lo) | ((u32)f2bf(hi) << 16);
}
static __device__ __forceinline__ float bf2f(u32 u) {
  return __uint_as_float(u << 16);
}
// async 16B global->LDS copy (dest: wave-uniform base + lane*16)
static __device__ __forceinline__ void gload_lds16(const u16* g, u16* l) {
  __builtin_amdgcn_global_load_lds(
      (const __attribute__((address_space(1))) u32*)(g),
      (__attribute__((address_space(3))) u32*)(l), 16, 0, 0);
}

// ---------------------------------------------------------------- K1: gate (FROZEN — exact)
// K split in HALF — single interior seam at k=512.
__global__ __launch_bounds__(256) void k1_gate(const float* __restrict__ x,
                                               const float* __restrict__ gw,
                                               float* __restrict__ scoresT) {
  __shared__ __align__(16) float xs[128][64];
  __shared__ __align__(16) float gs[128][64];
  const int tb  = blockIdx.x * 64;
  const int tid = threadIdx.x;
  const int tx = tid & 15, ty = tid >> 4;

  float accC[4][4];
  float accT[4][4];
#pragma unroll
  for (int i = 0; i < 4; ++i)
#pragma unroll
    for (int j = 0; j < 4; ++j) { accC[i][j] = 0.f; accT[i][j] = 0.f; }

  for (int c = 0; c < 8; ++c) {
    const int k0 = c * 128;
    {
      const int t = tid & 63, ks = (tid >> 6) * 32;
      const float* src = x + (size_t)(tb + t) * TWO_D + k0 + ks;
#pragma unroll
      for (int i = 0; i < 8; ++i) {
        float4 v = reinterpret_cast<const float4*>(src)[i];
        xs[ks + i * 4 + 0][t] = v.x;
        xs[ks + i * 4 + 1][t] = v.y;
        xs[ks + i * 4 + 2][t] = v.z;
        xs[ks + i * 4 + 3][t] = v.w;
      }
      const float4* gsrc = reinterpret_cast<const float4*>(gw + (size_t)k0 * 64);
      float4* gdst = reinterpret_cast<float4*>(&gs[0][0]);
#pragma unroll
      for (int i = 0; i < 8; ++i) gdst[tid + i * 256] = gsrc[tid + i * 256];
    }
    __syncthreads();
    for (int k = 0; k < 128; ++k) {
      float4 a4 = *reinterpret_cast<float4*>(&xs[k][tx * 4]);
      float4 b4 = *reinterpret_cast<float4*>(&gs[k][ty * 4]);
      float av[4] = {a4.x, a4.y, a4.z, a4.w};
      float bv[4] = {b4.x, b4.y, b4.z, b4.w};
#pragma unroll
      for (int i = 0; i < 4; ++i)
#pragma unroll
        for (int j = 0; j < 4; ++j) accC[i][j] = fmaf(bv[i], av[j], accC[i][j]);
    }
    __syncthreads();
    if (c == 3 || c == 7) {
#pragma unroll
      for (int i = 0; i < 4; ++i)
#pragma unroll
        for (int j = 0; j < 4; ++j) {
          accT[i][j] = accT[i][j] + accC[i][j];
          accC[i][j] = 0.f;
        }
    }
  }
#pragma unroll
  for (int i = 0; i < 4; ++i) {
    float4 v = make_float4(accT[i][0], accT[i][1], accT[i][2], accT[i][3]);
    *reinterpret_cast<float4*>(&scoresT[(size_t)(ty * 4 + i) * B_T + tb + tx * 4]) = v;
  }
}

// ---------------------------------------------------------------- K2: top-k (FROZEN)
__global__ __launch_bounds__(256) void k2_topk(const float* __restrict__ scoresT,
                                               int* __restrict__ topk_idx,
                                               float* __restrict__ topk_scr) {
  const int e = blockIdx.x, tid = threadIdx.x;
  const float* row = scoresT + (size_t)e * B_T;
  __shared__ u32 hist[256];
  __shared__ u32 s_prefix, s_r;
  __shared__ u32 cnt_gt, cnt_eq;
  __shared__ u64 skey[512];
  __shared__ u32 tie[512];

  if (tid == 0) { s_prefix = 0; s_r = KCAP; }
  u32 prefmask = 0;
  __syncthreads();

  for (int pass = 0; pass < 4; ++pass) {
    const int shift = 24 - 8 * pass;
    hist[tid] = 0;
    __syncthreads();
    const u32 prefix = s_prefix;
    for (int t = tid; t < B_T; t += 256) {
      u32 m = mono_of(row[t]);
      if ((m & prefmask) == prefix) atomicAdd(&hist[(m >> shift) & 0xFFu], 1u);
    }
    __syncthreads();
    if (tid == 0) {
      u32 r = s_r, cum = 0;
      int sel = 0;
      for (int b = 255; b >= 0; --b) {
        if (cum + hist[b] >= r) { sel = b; s_r = r - cum; break; }
        cum += hist[b];
      }
      s_prefix = prefix | ((u32)sel << shift);
    }
    prefmask |= (0xFFu << shift);
    __syncthreads();
  }

  const u32 kmono = s_prefix;
  const u32 rneed = s_r;
  if (tid == 0) { cnt_gt = 0; cnt_eq = 0; }
  tie[tid] = 0xFFFFFFFFu;
  tie[tid + 256] = 0xFFFFFFFFu;
  __syncthreads();

  for (int t = tid; t < B_T; t += 256) {
    u32 m = mono_of(row[t]);
    if (m > kmono) {
      u32 p = atomicAdd(&cnt_gt, 1u);
      if (p < 512) skey[p] = ((u64)(~m) << 32) | (u32)t;
    } else if (m == kmono) {
      u32 p = atomicAdd(&cnt_eq, 1u);
      if (p < 512) tie[p] = (u32)t;
    }
  }
  __syncthreads();

  for (int kk = 2; kk <= 512; kk <<= 1) {
    for (int j = kk >> 1; j > 0; j >>= 1) {
      __syncthreads();
#pragma unroll
      for (int base = 0; base < 512; base += 256) {
        int i = base + tid;
        int ixj = i ^ j;
        if (ixj > i) {
          u32 a = tie[i], b = tie[ixj];
          bool up = ((i & kk) == 0);
          if ((a > b) == up) { tie[i] = b; tie[ixj] = a; }
        }
      }
    }
  }
  __syncthreads();

  const u32 ngt = cnt_gt;
  for (u32 i = tid; i < rneed; i += 256) skey[ngt + i] = ((u64)(~kmono) << 32) | tie[i];
  __syncthreads();

  for (int kk = 2; kk <= 512; kk <<= 1) {
    for (int j = kk >> 1; j > 0; j >>= 1) {
      __syncthreads();
#pragma unroll
      for (int base = 0; base < 512; base += 256) {
        int i = base + tid;
        int ixj = i ^ j;
        if (ixj > i) {
          u64 a = skey[i], b = skey[ixj];
          bool up = ((i & kk) == 0);
          if ((a > b) == up) { skey[i] = b; skey[ixj] = a; }
        }
      }
    }
  }
  __syncthreads();

#pragma unroll
  for (int base = 0; base < 512; base += 256) {
    int i = base + tid;
    u64 kv = skey[i];
    u32 idx = (u32)kv;
    u32 m = ~((u32)(kv >> 32));
    topk_idx[e * KCAP + i] = (int)idx;
    topk_scr[e * KCAP + i] = score_from_mono(m);
  }
}

// ---------------------------------------------------------------- K2b: invert scatter
__global__ void k2b_invert(const int* __restrict__ topk_idx, int* __restrict__ counts,
                           int* __restrict__ entries) {
  int gid = blockIdx.x * 256 + threadIdx.x;  // 32768
  int ep = gid & 63, jp = gid >> 6;
  int t = topk_idx[ep * KCAP + jp];
  int pos = atomicAdd(&counts[t], 1);
  entries[t * 64 + pos] = gid;
}

// ---------------------------------------------------------------- K3: W -> bf16 transposed
__global__ __launch_bounds__(256) void k3_wtrans(const float* __restrict__ w,
                                                 u16* __restrict__ wrT,
                                                 u16* __restrict__ wiT) {
  __shared__ float2 tr[32][33];
  const int bid = blockIdx.x;
  const int e = bid >> 8, tile = bid & 255;
  const int d0 = (tile >> 4) * 32, f0 = (tile & 15) * 32;
  const int tid = threadIdx.x;
  const int fl = tid & 31, dl0 = tid >> 5;
  const float* base = w + ((size_t)e * 512 + d0) * 1024 + (size_t)f0 * 2;
#pragma unroll
  for (int it = 0; it < 4; ++it) {
    int dl = dl0 + it * 8;
    float2 v = *reinterpret_cast<const float2*>(base + (size_t)dl * 1024 + fl * 2);
    tr[dl][fl] = v;
  }
  __syncthreads();
  const int d2 = (tid & 15) * 2, fl0 = tid >> 4;
#pragma unroll
  for (int it = 0; it < 2; ++it) {
    int f = fl0 + it * 16;
    float2 a = tr[d2][f], b = tr[d2 + 1][f];
    size_t off = ((size_t)e * 512 + f0 + f) * 512 + d0 + d2;
    *reinterpret_cast<u32*>(&wrT[off]) = f2bf2(a.x, b.x);
    *reinterpret_cast<u32*>(&wiT[off]) = f2bf2(a.y, b.y);
  }
}

// ---------------------------------------------------------------- K4: grouped complex GEMM
// 64x32 wave tiles (4 waves -> 128x64 per block), 4096 blocks, 4 blocks/CU.
// A reg-staged f32->bf16; B one gload_lds16 per thread per array;
// chunk-major LDS; two accumulators, sign folded at epilogue; bf16 stores.
__global__ __launch_bounds__(256, 4) void k4_gemm(
    const float* __restrict__ x, const int* __restrict__ topk_idx,
    const float* __restrict__ topk_scr, const u16* __restrict__ wrT,
    const u16* __restrict__ wiT, u16* __restrict__ yrw, u16* __restrict__ yiw) {
  const int bid = blockIdx.x;
  const int xcd = bid & 7, q = bid >> 3, t = q & 63, g = q >> 6;
  const int e = g * 8 + xcd;
  const int mb = t & 3, fb = (t >> 2) & 7, cn = t >> 5;
  const int m0 = mb * 128, f0 = fb * 64;

  // A chunk-major [4][128][8] (8KB each); B chunk-major [4][64][8] (4KB each)
  __shared__ __align__(16) u16 Ar[4096];
  __shared__ __align__(16) u16 Ai[4096];
  __shared__ __align__(16) u16 Bu[2048];
  __shared__ __align__(16) u16 Bv[2048];
  __shared__ int tok[128];
  __shared__ float scr[128];

  const int tid = threadIdx.x;
  if (tid < 128) {
    tok[tid] = topk_idx[e * KCAP + m0 + tid];
    scr[tid] = topk_scr[e * KCAP + m0 + tid];
  }
  __syncthreads();

  // A reg-staging: thread pair per row
  const int row = tid >> 1, half = tid & 1;
  const float* arow = x + (size_t)tok[row] * TWO_D + half * 32;
  // B async-staging: one entry per thread: row=tid&63, chunk=tid>>6
  const int rb_row = tid & 63, kb = (tid >> 6) * 8;
  const size_t brow = ((size_t)e * 512 + f0 + rb_row) * 512;
  const int wv = tid >> 6, ln = tid & 63;
  const int db = wv * 512;  // wave-uniform; lane*16B implicit

  const int mbase = (wv >> 1) * 64, nbase = (wv & 1) * 32;
  const int frow = ln & 15, fq = ln >> 4;
  const int ra = fq * 1024 + (mbase + frow) * 8;
  const int rb = fq * 512 + (nbase + frow) * 8;

  const u16* B1 = cn ? Bv : Bu;
  const u16* B2 = cn ? Bu : Bv;

  f32x4 acc1[4][2] = {};
  f32x4 acc2[4][2] = {};

  for (int step = 0; step < 16; ++step) {
    const int k0 = step * 32;
    gload_lds16(wrT + brow + k0 + kb, Bu + db);
    gload_lds16(wiT + brow + k0 + kb, Bv + db);
    {
      const float4* ap = reinterpret_cast<const float4*>(arow + (size_t)k0 * 2);
      u32 xr[8], xi[8];
#pragma unroll
      for (int i = 0; i < 8; ++i) {
        float4 v = ap[i];
        xr[i] = f2bf2(v.x, v.z);
        xi[i] = f2bf2(v.y, v.w);
      }
      uint4 wa, wb;
      wa.x = xr[0]; wa.y = xr[1]; wa.z = xr[2]; wa.w = xr[3];
      wb.x = xr[4]; wb.y = xr[5]; wb.z = xr[6]; wb.w = xr[7];
      *reinterpret_cast<uint4*>(&Ar[(2 * half) * 1024 + row * 8]) = wa;
      *reinterpret_cast<uint4*>(&Ar[(2 * half + 1) * 1024 + row * 8]) = wb;
      wa.x = xi[0]; wa.y = xi[1]; wa.z = xi[2]; wa.w = xi[3];
      wb.x = xi[4]; wb.y = xi[5]; wb.z = xi[6]; wb.w = xi[7];
      *reinterpret_cast<uint4*>(&Ai[(2 * half) * 1024 + row * 8]) = wa;
      *reinterpret_cast<uint4*>(&Ai[(2 * half + 1) * 1024 + row * 8]) = wb;
    }
    __syncthreads();

    bf16x8 ar[4], ai[4], b1[2], b2[2];
#pragma unroll
    for (int m = 0; m < 4; ++m) {
      ar[m] = *reinterpret_cast<const bf16x8*>(&Ar[ra + m * 128]);
      ai[m] = *reinterpret_cast<const bf16x8*>(&Ai[ra + m * 128]);
    }
#pragma unroll
    for (int n = 0; n < 2; ++n) {
      b1[n] = *reinterpret_cast<const bf16x8*>(&B1[rb + n * 128]);
      b2[n] = *reinterpret_cast<const bf16x8*>(&B2[rb + n * 128]);
    }
#pragma unroll
    for (int m = 0; m < 4; ++m)
#pragma unroll
      for (int n = 0; n < 2; ++n) {
        acc1[m][n] = __builtin_amdgcn_mfma_f32_16x16x32_bf16(ar[m], b1[n], acc1[m][n], 0, 0, 0);
        acc2[m][n] = __builtin_amdgcn_mfma_f32_16x16x32_bf16(ai[m], b2[n], acc2[m][n], 0, 0, 0);
      }
    __syncthreads();
  }

  // epilogue: val = (cn ? a1+a2 : a1-a2) * scr; plain bf16 store
  u16* dst = cn ? yiw : yrw;
  const int rr = fq * 4;
#pragma unroll
  for (int m = 0; m < 4; ++m) {
#pragma unroll
    for (int r = 0; r < 4; ++r) {
      const int jl = mbase + m * 16 + rr + r;
      const float ww = scr[jl];
      const size_t ybase = ((size_t)e * KCAP + m0 + jl) * DD;
#pragma unroll
      for (int n = 0; n < 2; ++n) {
        const int fg = f0 + nbase + n * 16 + frow;
        float v1 = acc1[m][n][r], v2 = acc2[m][n][r];
        float val = cn ? (v1 + v2) : (v1 - v2);
        dst[ybase + fg] = f2bf(val * ww);
      }
    }
  }
}

// ---------------------------------------------------------------- K5: gather + GELU
#define GELU(z) (0.5f * (z) * (1.0f + erff((z)*0.70710678118654752440f)))
__global__ __launch_bounds__(256) void k5_gather(
    const u16* __restrict__ yrw, const u16* __restrict__ yiw,
    const int* __restrict__ counts, const int* __restrict__ entries,
    const float* __restrict__ bias, float* __restrict__ out) {
  const int t = blockIdx.x;
  const int tid = threadIdx.x;
  const int c = counts[t];
  const float inv = 1.0f / (float)(c > 0 ? c : 1);
  const int f0 = tid * 2;
  float sr0 = 0.f, sr1 = 0.f, si0 = 0.f, si1 = 0.f;
  for (int i = 0; i < c; ++i) {
    int srcrow = entries[t * 64 + i];
    size_t off = (size_t)srcrow * DD + f0;
    u32 pr = *reinterpret_cast<const u32*>(yrw + off);
    u32 pi = *reinterpret_cast<const u32*>(yiw + off);
    sr0 += bf2f(pr & 0xFFFFu); sr1 += bf2f(pr >> 16);
    si0 += bf2f(pi & 0xFFFFu); si1 += bf2f(pi >> 16);
  }
  const float b0 = bias[f0], b1 = bias[f0 + 1];
  float v0 = sr0 * inv + b0;
  float v1 = si0 * inv + b0;
  float v2 = sr1 * inv + b1;
  float v3 = si1 * inv + b1;
  float4 o = make_float4(GELU(v0), GELU(v1), GELU(v2), GELU(v3));
  *reinterpret_cast<float4*>(&out[(size_t)t * TWO_D + f0 * 2]) = o;
}

// ---------------------------------------------------------------- launch
extern "C" void kernel_launch(void* const* d_in, const int* in_sizes, int n_in,
                              void* d_out, int out_size, void* d_ws, size_t ws_size,
                              hipStream_t stream) {
  const float* x    = (const float*)d_in[0];
  const float* gw   = (const float*)d_in[1];
  const float* w    = (const float*)d_in[2];
  const float* bias = (const float*)d_in[3];
  float* out = (float*)d_out;

  char* ws = (char*)d_ws;
  u16*   yrw     = (u16*)(ws);                  //  32 MiB (aliases scoresT)
  float* scoresT = (float*)(ws);                //   4 MiB (dead before k4)
  u16*   yiw     = (u16*)(ws + 33554432);       //  32 MiB
  int*   tidx    = (int*)(ws + 67108864);       //  128 KiB
  float* tscr    = (float*)(ws + 67239936);     //  128 KiB
  int*   counts  = (int*)(ws + 67371008);       //  64 KiB
  int*   entries = (int*)(ws + 67436544);       //   4 MiB
  u16*   wrT     = (u16*)(ws + 71630848);       //  32 MiB
  u16*   wiT     = (u16*)(ws + 105185280);      //  32 MiB  (end: 138,739,712)

  hipMemsetAsync(counts, 0, B_T * sizeof(int), stream);
  k1_gate<<<B_T / 64, 256, 0, stream>>>(x, gw, scoresT);
  k2_topk<<<NE, 256, 0, stream>>>(scoresT, tidx, tscr);
  k2b_invert<<<(NE * KCAP) / 256, 256, 0, stream>>>(tidx, counts, entries);
  k3_wtrans<<<NE * 256, 256, 0, stream>>>(w, wrT, wiT);
  k4_gemm<<<4096, 256, 0, stream>>>(x, tidx, tscr, wrT, wiT, yrw, yiw);
  k5_gather<<<B_T, 256, 0, stream>>>(yrw, yiw, counts, entries, bias, out);
}

// Round 16
// 360.321 us; speedup vs baseline: 2.1966x; 2.1966x over previous
//
#include <hip/hip_runtime.h>
#include <stdint.h>
#include <math.h>

typedef uint32_t u32;
typedef uint64_t u64;
typedef unsigned short u16;

#define B_T    16384
#define DD     512
#define NE     64
#define KCAP   512
#define TWO_D  1024

typedef __attribute__((ext_vector_type(8))) short bf16x8;
typedef __attribute__((ext_vector_type(4))) float f32x4;
typedef __attribute__((ext_vector_type(4))) u32 u32x4;

static __device__ __forceinline__ u32 mono_of(float s) {
  u32 b = __float_as_uint(s);
  return (b & 0x80000000u) ? ~b : (b | 0x80000000u);
}
static __device__ __forceinline__ float score_from_mono(u32 m) {
  u32 b = (m & 0x80000000u) ? (m ^ 0x80000000u) : ~m;
  return __uint_as_float(b);
}
static __device__ __forceinline__ u16 f2bf(float f) {
  u32 b = __float_as_uint(f);
  b += 0x7FFFu + ((b >> 16) & 1u);
  return (u16)(b >> 16);
}
static __device__ __forceinline__ u32 f2bf2(float lo, float hi) {
  return (u32)f2bf(lo) | ((u32)f2bf(hi) << 16);
}
static __device__ __forceinline__ float bf2f(u32 u) {
  return __uint_as_float(u << 16);
}
// async 16B global->LDS copy (dest: wave-uniform base + lane*16)
static __device__ __forceinline__ void gload_lds16(const u16* g, u16* l) {
  __builtin_amdgcn_global_load_lds(
      (const __attribute__((address_space(1))) u32*)(g),
      (__attribute__((address_space(3))) u32*)(l), 16, 0, 0);
}
// negate all 8 bf16 lanes of a fragment (sign-bit XOR)
static __device__ __forceinline__ bf16x8 negbf8(bf16x8 v) {
  u32x4 u;
  u32x4 s = *reinterpret_cast<u32x4*>(&v);
  u[0] = s[0] ^ 0x80008000u;
  u[1] = s[1] ^ 0x80008000u;
  u[2] = s[2] ^ 0x80008000u;
  u[3] = s[3] ^ 0x80008000u;
  return *reinterpret_cast<bf16x8*>(&u);
}

// ---------------------------------------------------------------- K1: gate (FROZEN — exact)
// K split in HALF — single interior seam at k=512.
__global__ __launch_bounds__(256) void k1_gate(const float* __restrict__ x,
                                               const float* __restrict__ gw,
                                               float* __restrict__ scoresT) {
  __shared__ __align__(16) float xs[128][64];
  __shared__ __align__(16) float gs[128][64];
  const int tb  = blockIdx.x * 64;
  const int tid = threadIdx.x;
  const int tx = tid & 15, ty = tid >> 4;

  float accC[4][4];
  float accT[4][4];
#pragma unroll
  for (int i = 0; i < 4; ++i)
#pragma unroll
    for (int j = 0; j < 4; ++j) { accC[i][j] = 0.f; accT[i][j] = 0.f; }

  for (int c = 0; c < 8; ++c) {
    const int k0 = c * 128;
    {
      const int t = tid & 63, ks = (tid >> 6) * 32;
      const float* src = x + (size_t)(tb + t) * TWO_D + k0 + ks;
#pragma unroll
      for (int i = 0; i < 8; ++i) {
        float4 v = reinterpret_cast<const float4*>(src)[i];
        xs[ks + i * 4 + 0][t] = v.x;
        xs[ks + i * 4 + 1][t] = v.y;
        xs[ks + i * 4 + 2][t] = v.z;
        xs[ks + i * 4 + 3][t] = v.w;
      }
      const float4* gsrc = reinterpret_cast<const float4*>(gw + (size_t)k0 * 64);
      float4* gdst = reinterpret_cast<float4*>(&gs[0][0]);
#pragma unroll
      for (int i = 0; i < 8; ++i) gdst[tid + i * 256] = gsrc[tid + i * 256];
    }
    __syncthreads();
    for (int k = 0; k < 128; ++k) {
      float4 a4 = *reinterpret_cast<float4*>(&xs[k][tx * 4]);
      float4 b4 = *reinterpret_cast<float4*>(&gs[k][ty * 4]);
      float av[4] = {a4.x, a4.y, a4.z, a4.w};
      float bv[4] = {b4.x, b4.y, b4.z, b4.w};
#pragma unroll
      for (int i = 0; i < 4; ++i)
#pragma unroll
        for (int j = 0; j < 4; ++j) accC[i][j] = fmaf(bv[i], av[j], accC[i][j]);
    }
    __syncthreads();
    if (c == 3 || c == 7) {
#pragma unroll
      for (int i = 0; i < 4; ++i)
#pragma unroll
        for (int j = 0; j < 4; ++j) {
          accT[i][j] = accT[i][j] + accC[i][j];
          accC[i][j] = 0.f;
        }
    }
  }
#pragma unroll
  for (int i = 0; i < 4; ++i) {
    float4 v = make_float4(accT[i][0], accT[i][1], accT[i][2], accT[i][3]);
    *reinterpret_cast<float4*>(&scoresT[(size_t)(ty * 4 + i) * B_T + tb + tx * 4]) = v;
  }
}

// ---------------------------------------------------------------- K2: top-k (FROZEN)
__global__ __launch_bounds__(256) void k2_topk(const float* __restrict__ scoresT,
                                               int* __restrict__ topk_idx,
                                               float* __restrict__ topk_scr) {
  const int e = blockIdx.x, tid = threadIdx.x;
  const float* row = scoresT + (size_t)e * B_T;
  __shared__ u32 hist[256];
  __shared__ u32 s_prefix, s_r;
  __shared__ u32 cnt_gt, cnt_eq;
  __shared__ u64 skey[512];
  __shared__ u32 tie[512];

  if (tid == 0) { s_prefix = 0; s_r = KCAP; }
  u32 prefmask = 0;
  __syncthreads();

  for (int pass = 0; pass < 4; ++pass) {
    const int shift = 24 - 8 * pass;
    hist[tid] = 0;
    __syncthreads();
    const u32 prefix = s_prefix;
    for (int t = tid; t < B_T; t += 256) {
      u32 m = mono_of(row[t]);
      if ((m & prefmask) == prefix) atomicAdd(&hist[(m >> shift) & 0xFFu], 1u);
    }
    __syncthreads();
    if (tid == 0) {
      u32 r = s_r, cum = 0;
      int sel = 0;
      for (int b = 255; b >= 0; --b) {
        if (cum + hist[b] >= r) { sel = b; s_r = r - cum; break; }
        cum += hist[b];
      }
      s_prefix = prefix | ((u32)sel << shift);
    }
    prefmask |= (0xFFu << shift);
    __syncthreads();
  }

  const u32 kmono = s_prefix;
  const u32 rneed = s_r;
  if (tid == 0) { cnt_gt = 0; cnt_eq = 0; }
  tie[tid] = 0xFFFFFFFFu;
  tie[tid + 256] = 0xFFFFFFFFu;
  __syncthreads();

  for (int t = tid; t < B_T; t += 256) {
    u32 m = mono_of(row[t]);
    if (m > kmono) {
      u32 p = atomicAdd(&cnt_gt, 1u);
      if (p < 512) skey[p] = ((u64)(~m) << 32) | (u32)t;
    } else if (m == kmono) {
      u32 p = atomicAdd(&cnt_eq, 1u);
      if (p < 512) tie[p] = (u32)t;
    }
  }
  __syncthreads();

  for (int kk = 2; kk <= 512; kk <<= 1) {
    for (int j = kk >> 1; j > 0; j >>= 1) {
      __syncthreads();
#pragma unroll
      for (int base = 0; base < 512; base += 256) {
        int i = base + tid;
        int ixj = i ^ j;
        if (ixj > i) {
          u32 a = tie[i], b = tie[ixj];
          bool up = ((i & kk) == 0);
          if ((a > b) == up) { tie[i] = b; tie[ixj] = a; }
        }
      }
    }
  }
  __syncthreads();

  const u32 ngt = cnt_gt;
  for (u32 i = tid; i < rneed; i += 256) skey[ngt + i] = ((u64)(~kmono) << 32) | tie[i];
  __syncthreads();

  for (int kk = 2; kk <= 512; kk <<= 1) {
    for (int j = kk >> 1; j > 0; j >>= 1) {
      __syncthreads();
#pragma unroll
      for (int base = 0; base < 512; base += 256) {
        int i = base + tid;
        int ixj = i ^ j;
        if (ixj > i) {
          u64 a = skey[i], b = skey[ixj];
          bool up = ((i & kk) == 0);
          if ((a > b) == up) { skey[i] = b; skey[ixj] = a; }
        }
      }
    }
  }
  __syncthreads();

#pragma unroll
  for (int base = 0; base < 512; base += 256) {
    int i = base + tid;
    u64 kv = skey[i];
    u32 idx = (u32)kv;
    u32 m = ~((u32)(kv >> 32));
    topk_idx[e * KCAP + i] = (int)idx;
    topk_scr[e * KCAP + i] = score_from_mono(m);
  }
}

// ---------------------------------------------------------------- K2b: invert scatter
__global__ void k2b_invert(const int* __restrict__ topk_idx, int* __restrict__ counts,
                           int* __restrict__ entries) {
  int gid = blockIdx.x * 256 + threadIdx.x;  // 32768
  int ep = gid & 63, jp = gid >> 6;
  int t = topk_idx[ep * KCAP + jp];
  int pos = atomicAdd(&counts[t], 1);
  entries[t * 64 + pos] = gid;
}

// ---------------------------------------------------------------- K3: W -> bf16 transposed
__global__ __launch_bounds__(256) void k3_wtrans(const float* __restrict__ w,
                                                 u16* __restrict__ wrT,
                                                 u16* __restrict__ wiT) {
  __shared__ float2 tr[32][33];
  const int bid = blockIdx.x;
  const int e = bid >> 8, tile = bid & 255;
  const int d0 = (tile >> 4) * 32, f0 = (tile & 15) * 32;
  const int tid = threadIdx.x;
  const int fl = tid & 31, dl0 = tid >> 5;
  const float* base = w + ((size_t)e * 512 + d0) * 1024 + (size_t)f0 * 2;
#pragma unroll
  for (int it = 0; it < 4; ++it) {
    int dl = dl0 + it * 8;
    float2 v = *reinterpret_cast<const float2*>(base + (size_t)dl * 1024 + fl * 2);
    tr[dl][fl] = v;
  }
  __syncthreads();
  const int d2 = (tid & 15) * 2, fl0 = tid >> 4;
#pragma unroll
  for (int it = 0; it < 2; ++it) {
    int f = fl0 + it * 16;
    float2 a = tr[d2][f], b = tr[d2 + 1][f];
    size_t off = ((size_t)e * 512 + f0 + f) * 512 + d0 + d2;
    *reinterpret_cast<u32*>(&wrT[off]) = f2bf2(a.x, b.x);
    *reinterpret_cast<u32*>(&wiT[off]) = f2bf2(a.y, b.y);
  }
}

// ---------------------------------------------------------------- K4: grouped complex GEMM
// cn-MERGED: each block computes BOTH yr and yi for its 128x128 tile.
// acc_r = xr*wr - xi*wi (wi negated in-register), acc_i = xr*wi + xi*wr.
// Grid 1024 (half of R14) -> half the staging/barriers, same total MFMA.
__global__ __launch_bounds__(256, 2) void k4_gemm(
    const float* __restrict__ x, const int* __restrict__ topk_idx,
    const float* __restrict__ topk_scr, const u16* __restrict__ wrT,
    const u16* __restrict__ wiT, u16* __restrict__ yrw, u16* __restrict__ yiw) {
  const int bid = blockIdx.x;
  const int xcd = bid & 7, q = bid >> 3, t = q & 15, g = q >> 4;
  const int e = g * 8 + xcd;
  const int mb = t & 3, fb = t >> 2;
  const int m0 = mb * 128, f0 = fb * 128;

  // chunk-major [4][128][8] u16 (8KB each)
  __shared__ __align__(16) u16 Ar[4096];
  __shared__ __align__(16) u16 Ai[4096];
  __shared__ __align__(16) u16 Bu[4096];
  __shared__ __align__(16) u16 Bv[4096];
  __shared__ int tok[128];
  __shared__ float scr[128];

  const int tid = threadIdx.x;
  if (tid < 128) {
    tok[tid] = topk_idx[e * KCAP + m0 + tid];
    scr[tid] = topk_scr[e * KCAP + m0 + tid];
  }
  __syncthreads();

  // A reg-staging: thread pair per row
  const int row = tid >> 1, half = tid & 1;
  const float* arow = x + (size_t)tok[row] * TWO_D + half * 32;
  // B async-staging: entries E = i*256+tid; row=E&127, chunk=E>>7
  const int r0  = tid & 127;
  const int ka0 = (tid >> 7) * 8;
  const int ka1 = ka0 + 16;
  const size_t brow = ((size_t)e * 512 + f0 + r0) * 512;
  const int wv = tid >> 6, ln = tid & 63;
  const int d0 = wv * 512;
  const int d1 = 2048 + wv * 512;

  const int mbase = (wv >> 1) * 64, nbase = (wv & 1) * 64;
  const int frow = ln & 15, fq = ln >> 4;
  const int ra = fq * 1024 + (mbase + frow) * 8;
  const int rb = fq * 1024 + (nbase + frow) * 8;

  f32x4 accR[4][4] = {};
  f32x4 accI[4][4] = {};

  for (int step = 0; step < 16; ++step) {
    const int k0 = step * 32;
    gload_lds16(wrT + brow + k0 + ka0, Bu + d0);
    gload_lds16(wrT + brow + k0 + ka1, Bu + d1);
    gload_lds16(wiT + brow + k0 + ka0, Bv + d0);
    gload_lds16(wiT + brow + k0 + ka1, Bv + d1);
    {
      const float4* ap = reinterpret_cast<const float4*>(arow + (size_t)k0 * 2);
      u32 xr[8], xi[8];
#pragma unroll
      for (int i = 0; i < 8; ++i) {
        float4 v = ap[i];
        xr[i] = f2bf2(v.x, v.z);
        xi[i] = f2bf2(v.y, v.w);
      }
      uint4 wa, wb;
      wa.x = xr[0]; wa.y = xr[1]; wa.z = xr[2]; wa.w = xr[3];
      wb.x = xr[4]; wb.y = xr[5]; wb.z = xr[6]; wb.w = xr[7];
      *reinterpret_cast<uint4*>(&Ar[(2 * half) * 1024 + row * 8]) = wa;
      *reinterpret_cast<uint4*>(&Ar[(2 * half + 1) * 1024 + row * 8]) = wb;
      wa.x = xi[0]; wa.y = xi[1]; wa.z = xi[2]; wa.w = xi[3];
      wb.x = xi[4]; wb.y = xi[5]; wb.z = xi[6]; wb.w = xi[7];
      *reinterpret_cast<uint4*>(&Ai[(2 * half) * 1024 + row * 8]) = wa;
      *reinterpret_cast<uint4*>(&Ai[(2 * half + 1) * 1024 + row * 8]) = wb;
    }
    __syncthreads();

    bf16x8 ar[4], ai[4], bu[4], bv[4];
#pragma unroll
    for (int m = 0; m < 4; ++m) {
      ar[m] = *reinterpret_cast<const bf16x8*>(&Ar[ra + m * 128]);
      ai[m] = *reinterpret_cast<const bf16x8*>(&Ai[ra + m * 128]);
    }
#pragma unroll
    for (int n = 0; n < 4; ++n) {
      bu[n] = *reinterpret_cast<const bf16x8*>(&Bu[rb + n * 128]);
      bv[n] = *reinterpret_cast<const bf16x8*>(&Bv[rb + n * 128]);
    }
#pragma unroll
    for (int m = 0; m < 4; ++m)
#pragma unroll
      for (int n = 0; n < 4; ++n) {
        bf16x8 bw = negbf8(bv[n]);
        accR[m][n] = __builtin_amdgcn_mfma_f32_16x16x32_bf16(ar[m], bu[n], accR[m][n], 0, 0, 0);
        accR[m][n] = __builtin_amdgcn_mfma_f32_16x16x32_bf16(ai[m], bw,    accR[m][n], 0, 0, 0);
        accI[m][n] = __builtin_amdgcn_mfma_f32_16x16x32_bf16(ar[m], bv[n], accI[m][n], 0, 0, 0);
        accI[m][n] = __builtin_amdgcn_mfma_f32_16x16x32_bf16(ai[m], bu[n], accI[m][n], 0, 0, 0);
      }
    __syncthreads();
  }

  // epilogue: weight by score; bf16 stores to both components
  const int rr = fq * 4;
#pragma unroll
  for (int m = 0; m < 4; ++m) {
#pragma unroll
    for (int r = 0; r < 4; ++r) {
      const int jl = mbase + m * 16 + rr + r;
      const float ww = scr[jl];
      const size_t ybase = ((size_t)e * KCAP + m0 + jl) * DD;
#pragma unroll
      for (int n = 0; n < 4; ++n) {
        const int fg = f0 + nbase + n * 16 + frow;
        yrw[ybase + fg] = f2bf(accR[m][n][r] * ww);
        yiw[ybase + fg] = f2bf(accI[m][n][r] * ww);
      }
    }
  }
}

// ---------------------------------------------------------------- K5: gather + GELU
#define GELU(z) (0.5f * (z) * (1.0f + erff((z)*0.70710678118654752440f)))
__global__ __launch_bounds__(256) void k5_gather(
    const u16* __restrict__ yrw, const u16* __restrict__ yiw,
    const int* __restrict__ counts, const int* __restrict__ entries,
    const float* __restrict__ bias, float* __restrict__ out) {
  const int t = blockIdx.x;
  const int tid = threadIdx.x;
  const int c = counts[t];
  const float inv = 1.0f / (float)(c > 0 ? c : 1);
  const int f0 = tid * 2;
  float sr0 = 0.f, sr1 = 0.f, si0 = 0.f, si1 = 0.f;
  for (int i = 0; i < c; ++i) {
    int srcrow = entries[t * 64 + i];
    size_t off = (size_t)srcrow * DD + f0;
    u32 pr = *reinterpret_cast<const u32*>(yrw + off);
    u32 pi = *reinterpret_cast<const u32*>(yiw + off);
    sr0 += bf2f(pr & 0xFFFFu); sr1 += bf2f(pr >> 16);
    si0 += bf2f(pi & 0xFFFFu); si1 += bf2f(pi >> 16);
  }
  const float b0 = bias[f0], b1 = bias[f0 + 1];
  float v0 = sr0 * inv + b0;
  float v1 = si0 * inv + b0;
  float v2 = sr1 * inv + b1;
  float v3 = si1 * inv + b1;
  float4 o = make_float4(GELU(v0), GELU(v1), GELU(v2), GELU(v3));
  *reinterpret_cast<float4*>(&out[(size_t)t * TWO_D + f0 * 2]) = o;
}

// ---------------------------------------------------------------- launch
extern "C" void kernel_launch(void* const* d_in, const int* in_sizes, int n_in,
                              void* d_out, int out_size, void* d_ws, size_t ws_size,
                              hipStream_t stream) {
  const float* x    = (const float*)d_in[0];
  const float* gw   = (const float*)d_in[1];
  const float* w    = (const float*)d_in[2];
  const float* bias = (const float*)d_in[3];
  float* out = (float*)d_out;

  char* ws = (char*)d_ws;
  u16*   yrw     = (u16*)(ws);                  //  32 MiB (aliases scoresT)
  float* scoresT = (float*)(ws);                //   4 MiB (dead before k4)
  u16*   yiw     = (u16*)(ws + 33554432);       //  32 MiB
  int*   tidx    = (int*)(ws + 67108864);       //  128 KiB
  float* tscr    = (float*)(ws + 67239936);     //  128 KiB
  int*   counts  = (int*)(ws + 67371008);       //  64 KiB
  int*   entries = (int*)(ws + 67436544);       //   4 MiB
  u16*   wrT     = (u16*)(ws + 71630848);       //  32 MiB
  u16*   wiT     = (u16*)(ws + 105185280);      //  32 MiB  (end: 138,739,712)

  hipMemsetAsync(counts, 0, B_T * sizeof(int), stream);
  k1_gate<<<B_T / 64, 256, 0, stream>>>(x, gw, scoresT);
  k2_topk<<<NE, 256, 0, stream>>>(scoresT, tidx, tscr);
  k2b_invert<<<(NE * KCAP) / 256, 256, 0, stream>>>(tidx, counts, entries);
  k3_wtrans<<<NE * 256, 256, 0, stream>>>(w, wrT, wiT);
  k4_gemm<<<1024, 256, 0, stream>>>(x, tidx, tscr, wrT, wiT, yrw, yiw);
  k5_gather<<<B_T, 256, 0, stream>>>(yrw, yiw, counts, entries, bias, out);
}

// Round 17
// 340.375 us; speedup vs baseline: 2.3253x; 1.0586x over previous
//
#include <hip/hip_runtime.h>
#include <stdint.h>
#include <math.h>

typedef uint32_t u32;
typedef uint64_t u64;
typedef unsigned short u16;

#define B_T    16384
#define DD     512
#define NE     64
#define KCAP   512
#define TWO_D  1024

typedef __attribute__((ext_vector_type(8))) short bf16x8;
typedef __attribute__((ext_vector_type(4))) float f32x4;
typedef __attribute__((ext_vector_type(4))) u32 u32x4;

static __device__ __forceinline__ u32 mono_of(float s) {
  u32 b = __float_as_uint(s);
  return (b & 0x80000000u) ? ~b : (b | 0x80000000u);
}
static __device__ __forceinline__ float score_from_mono(u32 m) {
  u32 b = (m & 0x80000000u) ? (m ^ 0x80000000u) : ~m;
  return __uint_as_float(b);
}
static __device__ __forceinline__ u16 f2bf(float f) {
  u32 b = __float_as_uint(f);
  b += 0x7FFFu + ((b >> 16) & 1u);
  return (u16)(b >> 16);
}
static __device__ __forceinline__ u32 f2bf2(float lo, float hi) {
  return (u32)f2bf(lo) | ((u32)f2bf(hi) << 16);
}
static __device__ __forceinline__ float bf2f(u32 u) {
  return __uint_as_float(u << 16);
}
// single-instruction packed f32x2 -> bf16x2 (RTNE; fine vs 0.0314 threshold)
static __device__ __forceinline__ u32 cvtpk(float lo, float hi) {
  u32 r;
  asm("v_cvt_pk_bf16_f32 %0, %1, %2" : "=v"(r) : "v"(lo), "v"(hi));
  return r;
}
// async 16B global->LDS copy (dest: wave-uniform base + lane*16; src per-lane)
static __device__ __forceinline__ void gload_lds16(const u16* g, u16* l) {
  __builtin_amdgcn_global_load_lds(
      (const __attribute__((address_space(1))) u32*)(g),
      (__attribute__((address_space(3))) u32*)(l), 16, 0, 0);
}
static __device__ __forceinline__ bf16x8 negbf8(bf16x8 v) {
  u32x4 u;
  u32x4 s = *reinterpret_cast<u32x4*>(&v);
  u[0] = s[0] ^ 0x80008000u;
  u[1] = s[1] ^ 0x80008000u;
  u[2] = s[2] ^ 0x80008000u;
  u[3] = s[3] ^ 0x80008000u;
  return *reinterpret_cast<bf16x8*>(&u);
}

// ---------------------------------------------------------------- K0: x -> bf16 r/i split
__global__ __launch_bounds__(256) void k0_xconv(const float* __restrict__ x,
                                                u16* __restrict__ xrb,
                                                u16* __restrict__ xib) {
  int idx = blockIdx.x * 256 + threadIdx.x;  // 4,194,304 float4s (2 complex each)
  float4 v = reinterpret_cast<const float4*>(x)[idx];
  reinterpret_cast<u32*>(xrb)[idx] = f2bf2(v.x, v.z);
  reinterpret_cast<u32*>(xib)[idx] = f2bf2(v.y, v.w);
}

// ---------------------------------------------------------------- K1: gate (FROZEN — exact)
__global__ __launch_bounds__(256) void k1_gate(const float* __restrict__ x,
                                               const float* __restrict__ gw,
                                               float* __restrict__ scoresT) {
  __shared__ __align__(16) float xs[128][64];
  __shared__ __align__(16) float gs[128][64];
  const int tb  = blockIdx.x * 64;
  const int tid = threadIdx.x;
  const int tx = tid & 15, ty = tid >> 4;

  float accC[4][4];
  float accT[4][4];
#pragma unroll
  for (int i = 0; i < 4; ++i)
#pragma unroll
    for (int j = 0; j < 4; ++j) { accC[i][j] = 0.f; accT[i][j] = 0.f; }

  for (int c = 0; c < 8; ++c) {
    const int k0 = c * 128;
    {
      const int t = tid & 63, ks = (tid >> 6) * 32;
      const float* src = x + (size_t)(tb + t) * TWO_D + k0 + ks;
#pragma unroll
      for (int i = 0; i < 8; ++i) {
        float4 v = reinterpret_cast<const float4*>(src)[i];
        xs[ks + i * 4 + 0][t] = v.x;
        xs[ks + i * 4 + 1][t] = v.y;
        xs[ks + i * 4 + 2][t] = v.z;
        xs[ks + i * 4 + 3][t] = v.w;
      }
      const float4* gsrc = reinterpret_cast<const float4*>(gw + (size_t)k0 * 64);
      float4* gdst = reinterpret_cast<float4*>(&gs[0][0]);
#pragma unroll
      for (int i = 0; i < 8; ++i) gdst[tid + i * 256] = gsrc[tid + i * 256];
    }
    __syncthreads();
    for (int k = 0; k < 128; ++k) {
      float4 a4 = *reinterpret_cast<float4*>(&xs[k][tx * 4]);
      float4 b4 = *reinterpret_cast<float4*>(&gs[k][ty * 4]);
      float av[4] = {a4.x, a4.y, a4.z, a4.w};
      float bv[4] = {b4.x, b4.y, b4.z, b4.w};
#pragma unroll
      for (int i = 0; i < 4; ++i)
#pragma unroll
        for (int j = 0; j < 4; ++j) accC[i][j] = fmaf(bv[i], av[j], accC[i][j]);
    }
    __syncthreads();
    if (c == 3 || c == 7) {
#pragma unroll
      for (int i = 0; i < 4; ++i)
#pragma unroll
        for (int j = 0; j < 4; ++j) {
          accT[i][j] = accT[i][j] + accC[i][j];
          accC[i][j] = 0.f;
        }
    }
  }
#pragma unroll
  for (int i = 0; i < 4; ++i) {
    float4 v = make_float4(accT[i][0], accT[i][1], accT[i][2], accT[i][3]);
    *reinterpret_cast<float4*>(&scoresT[(size_t)(ty * 4 + i) * B_T + tb + tx * 4]) = v;
  }
}

// ---------------------------------------------------------------- K2: top-k (FROZEN) + fused invert
__global__ __launch_bounds__(256) void k2_topk(const float* __restrict__ scoresT,
                                               int* __restrict__ topk_idx,
                                               float* __restrict__ topk_scr,
                                               int* __restrict__ counts,
                                               int* __restrict__ entries) {
  const int e = blockIdx.x, tid = threadIdx.x;
  const float* row = scoresT + (size_t)e * B_T;
  __shared__ u32 hist[256];
  __shared__ u32 s_prefix, s_r;
  __shared__ u32 cnt_gt, cnt_eq;
  __shared__ u64 skey[512];
  __shared__ u32 tie[512];

  if (tid == 0) { s_prefix = 0; s_r = KCAP; }
  u32 prefmask = 0;
  __syncthreads();

  for (int pass = 0; pass < 4; ++pass) {
    const int shift = 24 - 8 * pass;
    hist[tid] = 0;
    __syncthreads();
    const u32 prefix = s_prefix;
    for (int t = tid; t < B_T; t += 256) {
      u32 m = mono_of(row[t]);
      if ((m & prefmask) == prefix) atomicAdd(&hist[(m >> shift) & 0xFFu], 1u);
    }
    __syncthreads();
    if (tid == 0) {
      u32 r = s_r, cum = 0;
      int sel = 0;
      for (int b = 255; b >= 0; --b) {
        if (cum + hist[b] >= r) { sel = b; s_r = r - cum; break; }
        cum += hist[b];
      }
      s_prefix = prefix | ((u32)sel << shift);
    }
    prefmask |= (0xFFu << shift);
    __syncthreads();
  }

  const u32 kmono = s_prefix;
  const u32 rneed = s_r;
  if (tid == 0) { cnt_gt = 0; cnt_eq = 0; }
  tie[tid] = 0xFFFFFFFFu;
  tie[tid + 256] = 0xFFFFFFFFu;
  __syncthreads();

  for (int t = tid; t < B_T; t += 256) {
    u32 m = mono_of(row[t]);
    if (m > kmono) {
      u32 p = atomicAdd(&cnt_gt, 1u);
      if (p < 512) skey[p] = ((u64)(~m) << 32) | (u32)t;
    } else if (m == kmono) {
      u32 p = atomicAdd(&cnt_eq, 1u);
      if (p < 512) tie[p] = (u32)t;
    }
  }
  __syncthreads();

  for (int kk = 2; kk <= 512; kk <<= 1) {
    for (int j = kk >> 1; j > 0; j >>= 1) {
      __syncthreads();
#pragma unroll
      for (int base = 0; base < 512; base += 256) {
        int i = base + tid;
        int ixj = i ^ j;
        if (ixj > i) {
          u32 a = tie[i], b = tie[ixj];
          bool up = ((i & kk) == 0);
          if ((a > b) == up) { tie[i] = b; tie[ixj] = a; }
        }
      }
    }
  }
  __syncthreads();

  const u32 ngt = cnt_gt;
  for (u32 i = tid; i < rneed; i += 256) skey[ngt + i] = ((u64)(~kmono) << 32) | tie[i];
  __syncthreads();

  for (int kk = 2; kk <= 512; kk <<= 1) {
    for (int j = kk >> 1; j > 0; j >>= 1) {
      __syncthreads();
#pragma unroll
      for (int base = 0; base < 512; base += 256) {
        int i = base + tid;
        int ixj = i ^ j;
        if (ixj > i) {
          u64 a = skey[i], b = skey[ixj];
          bool up = ((i & kk) == 0);
          if ((a > b) == up) { skey[i] = b; skey[ixj] = a; }
        }
      }
    }
  }
  __syncthreads();

#pragma unroll
  for (int base = 0; base < 512; base += 256) {
    int i = base + tid;
    u64 kv = skey[i];
    u32 idx = (u32)kv;
    u32 m = ~((u32)(kv >> 32));
    topk_idx[e * KCAP + i] = (int)idx;
    topk_scr[e * KCAP + i] = score_from_mono(m);
    // fused invert: y-row gid = i*64 + e scatters to token idx
    int pos = atomicAdd(&counts[idx], 1);
    entries[idx * 64 + pos] = i * 64 + e;
  }
}

// ---------------------------------------------------------------- K3: W -> bf16 transposed (float4 loads)
__global__ __launch_bounds__(256) void k3_wtrans(const float* __restrict__ w,
                                                 u16* __restrict__ wrT,
                                                 u16* __restrict__ wiT) {
  __shared__ float2 tr[32][33];
  const int bid = blockIdx.x;
  const int e = bid >> 8, tile = bid & 255;
  const int d0 = (tile >> 4) * 32, f0 = (tile & 15) * 32;
  const int tid = threadIdx.x;
  const int fl2 = tid & 15, dl0 = tid >> 4;  // 16 lanes x float4 (2 complex) per row
  const float* base = w + ((size_t)e * 512 + d0) * 1024 + (size_t)f0 * 2;
#pragma unroll
  for (int it = 0; it < 2; ++it) {
    int dl = dl0 + it * 16;
    float4 v = *reinterpret_cast<const float4*>(base + (size_t)dl * 1024 + fl2 * 4);
    tr[dl][fl2 * 2]     = make_float2(v.x, v.y);
    tr[dl][fl2 * 2 + 1] = make_float2(v.z, v.w);
  }
  __syncthreads();
  const int d2 = (tid & 15) * 2, fl0 = tid >> 4;
#pragma unroll
  for (int it = 0; it < 2; ++it) {
    int f = fl0 + it * 16;
    float2 a = tr[d2][f], b = tr[d2 + 1][f];
    size_t off = ((size_t)e * 512 + f0 + f) * 512 + d0 + d2;
    *reinterpret_cast<u32*>(&wrT[off]) = f2bf2(a.x, b.x);
    *reinterpret_cast<u32*>(&wiT[off]) = f2bf2(a.y, b.y);
  }
}

// ---------------------------------------------------------------- K4: grouped complex GEMM
// cn-merged 128x128 tiles; PRECONV=1: A via async gload from pre-converted
// bf16 (per-lane gathered source); PRECONV=0: reg-staged with v_cvt_pk.
template <int PRECONV>
__global__ __launch_bounds__(256, 2) void k4_gemm(
    const float* __restrict__ x, const u16* __restrict__ xrb,
    const u16* __restrict__ xib, const int* __restrict__ topk_idx,
    const float* __restrict__ topk_scr, const u16* __restrict__ wrT,
    const u16* __restrict__ wiT, u16* __restrict__ yrw, u16* __restrict__ yiw) {
  const int bid = blockIdx.x;
  const int xcd = bid & 7, q = bid >> 3, t = q & 15, g = q >> 4;
  const int e = g * 8 + xcd;
  const int mb = t & 3, fb = t >> 2;
  const int m0 = mb * 128, f0 = fb * 128;

  __shared__ __align__(16) u16 Ar[4096];
  __shared__ __align__(16) u16 Ai[4096];
  __shared__ __align__(16) u16 Bu[4096];
  __shared__ __align__(16) u16 Bv[4096];
  __shared__ int tok[128];
  __shared__ float scr[128];

  const int tid = threadIdx.x;
  if (tid < 128) {
    tok[tid] = topk_idx[e * KCAP + m0 + tid];
    scr[tid] = topk_scr[e * KCAP + m0 + tid];
  }
  __syncthreads();

  // staging geometry: entry E = i*256 + tid; row = E&127 (= tid&127 both i), chunk = E>>7
  const int r0  = tid & 127;
  const int ka0 = (tid >> 7) * 8;
  const int ka1 = ka0 + 16;
  const size_t brow = ((size_t)e * 512 + f0 + r0) * 512;
  const int wv = tid >> 6, ln = tid & 63;
  const int d0 = wv * 512;
  const int d1 = 2048 + wv * 512;

  // A source (both paths use tok[r0])
  const int mytok = tok[r0];
  const size_t arow_bf = (size_t)mytok * 512;          // PRECONV
  const int row = tid >> 1, half = tid & 1;             // !PRECONV
  const float* arow_f = x + (size_t)tok[row] * TWO_D + half * 32;

  const int mbase = (wv >> 1) * 64, nbase = (wv & 1) * 64;
  const int frow = ln & 15, fq = ln >> 4;
  const int ra = fq * 1024 + (mbase + frow) * 8;
  const int rb = fq * 1024 + (nbase + frow) * 8;

  f32x4 accR[4][4] = {};
  f32x4 accI[4][4] = {};

  for (int step = 0; step < 16; ++step) {
    const int k0 = step * 32;
    gload_lds16(wrT + brow + k0 + ka0, Bu + d0);
    gload_lds16(wrT + brow + k0 + ka1, Bu + d1);
    gload_lds16(wiT + brow + k0 + ka0, Bv + d0);
    gload_lds16(wiT + brow + k0 + ka1, Bv + d1);
    if (PRECONV) {
      gload_lds16(xrb + arow_bf + k0 + ka0, Ar + d0);
      gload_lds16(xrb + arow_bf + k0 + ka1, Ar + d1);
      gload_lds16(xib + arow_bf + k0 + ka0, Ai + d0);
      gload_lds16(xib + arow_bf + k0 + ka1, Ai + d1);
    } else {
      const float4* ap = reinterpret_cast<const float4*>(arow_f + (size_t)k0 * 2);
      u32 xr[8], xi[8];
#pragma unroll
      for (int i = 0; i < 8; ++i) {
        float4 v = ap[i];
        xr[i] = cvtpk(v.x, v.z);
        xi[i] = cvtpk(v.y, v.w);
      }
      uint4 wa, wb;
      wa.x = xr[0]; wa.y = xr[1]; wa.z = xr[2]; wa.w = xr[3];
      wb.x = xr[4]; wb.y = xr[5]; wb.z = xr[6]; wb.w = xr[7];
      *reinterpret_cast<uint4*>(&Ar[(2 * half) * 1024 + row * 8]) = wa;
      *reinterpret_cast<uint4*>(&Ar[(2 * half + 1) * 1024 + row * 8]) = wb;
      wa.x = xi[0]; wa.y = xi[1]; wa.z = xi[2]; wa.w = xi[3];
      wb.x = xi[4]; wb.y = xi[5]; wb.z = xi[6]; wb.w = xi[7];
      *reinterpret_cast<uint4*>(&Ai[(2 * half) * 1024 + row * 8]) = wa;
      *reinterpret_cast<uint4*>(&Ai[(2 * half + 1) * 1024 + row * 8]) = wb;
    }
    __syncthreads();

    bf16x8 ar[4], ai[4], bu[4], bv[4];
#pragma unroll
    for (int m = 0; m < 4; ++m) {
      ar[m] = *reinterpret_cast<const bf16x8*>(&Ar[ra + m * 128]);
      ai[m] = *reinterpret_cast<const bf16x8*>(&Ai[ra + m * 128]);
    }
#pragma unroll
    for (int n = 0; n < 4; ++n) {
      bu[n] = *reinterpret_cast<const bf16x8*>(&Bu[rb + n * 128]);
      bv[n] = *reinterpret_cast<const bf16x8*>(&Bv[rb + n * 128]);
    }
#pragma unroll
    for (int m = 0; m < 4; ++m)
#pragma unroll
      for (int n = 0; n < 4; ++n) {
        bf16x8 bw = negbf8(bv[n]);
        accR[m][n] = __builtin_amdgcn_mfma_f32_16x16x32_bf16(ar[m], bu[n], accR[m][n], 0, 0, 0);
        accR[m][n] = __builtin_amdgcn_mfma_f32_16x16x32_bf16(ai[m], bw,    accR[m][n], 0, 0, 0);
        accI[m][n] = __builtin_amdgcn_mfma_f32_16x16x32_bf16(ar[m], bv[n], accI[m][n], 0, 0, 0);
        accI[m][n] = __builtin_amdgcn_mfma_f32_16x16x32_bf16(ai[m], bu[n], accI[m][n], 0, 0, 0);
      }
    __syncthreads();
  }

  const int rr = fq * 4;
#pragma unroll
  for (int m = 0; m < 4; ++m) {
#pragma unroll
    for (int r = 0; r < 4; ++r) {
      const int jl = mbase + m * 16 + rr + r;
      const float ww = scr[jl];
      const size_t ybase = ((size_t)e * KCAP + m0 + jl) * DD;
#pragma unroll
      for (int n = 0; n < 4; ++n) {
        const int fg = f0 + nbase + n * 16 + frow;
        yrw[ybase + fg] = f2bf(accR[m][n][r] * ww);
        yiw[ybase + fg] = f2bf(accI[m][n][r] * ww);
      }
    }
  }
}

// ---------------------------------------------------------------- K5: gather + GELU
#define GELU(z) (0.5f * (z) * (1.0f + erff((z)*0.70710678118654752440f)))
__global__ __launch_bounds__(256) void k5_gather(
    const u16* __restrict__ yrw, const u16* __restrict__ yiw,
    const int* __restrict__ counts, const int* __restrict__ entries,
    const float* __restrict__ bias, float* __restrict__ out) {
  const int t = blockIdx.x;
  const int tid = threadIdx.x;
  const int c = counts[t];
  const float inv = 1.0f / (float)(c > 0 ? c : 1);
  const int f0 = tid * 2;
  float sr0 = 0.f, sr1 = 0.f, si0 = 0.f, si1 = 0.f;
  for (int i = 0; i < c; ++i) {
    int srcrow = entries[t * 64 + i];
    size_t off = (size_t)srcrow * DD + f0;
    u32 pr = *reinterpret_cast<const u32*>(yrw + off);
    u32 pi = *reinterpret_cast<const u32*>(yiw + off);
    sr0 += bf2f(pr & 0xFFFFu); sr1 += bf2f(pr >> 16);
    si0 += bf2f(pi & 0xFFFFu); si1 += bf2f(pi >> 16);
  }
  const float b0 = bias[f0], b1 = bias[f0 + 1];
  float v0 = sr0 * inv + b0;
  float v1 = si0 * inv + b0;
  float v2 = sr1 * inv + b1;
  float v3 = si1 * inv + b1;
  float4 o = make_float4(GELU(v0), GELU(v1), GELU(v2), GELU(v3));
  *reinterpret_cast<float4*>(&out[(size_t)t * TWO_D + f0 * 2]) = o;
}

// ---------------------------------------------------------------- launch
extern "C" void kernel_launch(void* const* d_in, const int* in_sizes, int n_in,
                              void* d_out, int out_size, void* d_ws, size_t ws_size,
                              hipStream_t stream) {
  const float* x    = (const float*)d_in[0];
  const float* gw   = (const float*)d_in[1];
  const float* w    = (const float*)d_in[2];
  const float* bias = (const float*)d_in[3];
  float* out = (float*)d_out;

  char* ws = (char*)d_ws;
  u16*   yrw     = (u16*)(ws);                  //  32 MiB (aliases scoresT)
  float* scoresT = (float*)(ws);                //   4 MiB (dead before k4)
  u16*   yiw     = (u16*)(ws + 33554432);       //  32 MiB
  int*   tidx    = (int*)(ws + 67108864);       //  128 KiB
  float* tscr    = (float*)(ws + 67239936);     //  128 KiB
  int*   counts  = (int*)(ws + 67371008);       //  64 KiB
  int*   entries = (int*)(ws + 67436544);       //   4 MiB
  u16*   wrT     = (u16*)(ws + 71630848);       //  32 MiB
  u16*   wiT     = (u16*)(ws + 105185280);      //  32 MiB  (end: 138,739,712)
  u16*   xrb     = (u16*)(ws + 138739712);      //  16 MiB  (preconv only)
  u16*   xib     = (u16*)(ws + 155516928);      //  16 MiB  (end: 172,294,144)

  const bool preconv = ws_size >= 172294144ull;

  hipMemsetAsync(counts, 0, B_T * sizeof(int), stream);
  k1_gate<<<B_T / 64, 256, 0, stream>>>(x, gw, scoresT);
  k2_topk<<<NE, 256, 0, stream>>>(scoresT, tidx, tscr, counts, entries);
  k3_wtrans<<<NE * 256, 256, 0, stream>>>(w, wrT, wiT);
  if (preconv) {
    k0_xconv<<<16384, 256, 0, stream>>>(x, xrb, xib);
    k4_gemm<1><<<1024, 256, 0, stream>>>(x, xrb, xib, tidx, tscr, wrT, wiT, yrw, yiw);
  } else {
    k4_gemm<0><<<1024, 256, 0, stream>>>(x, nullptr, nullptr, tidx, tscr, wrT, wiT, yrw, yiw);
  }
  k5_gather<<<B_T, 256, 0, stream>>>(yrw, yiw, counts, entries, bias, out);
}

// Round 18
// 287.189 us; speedup vs baseline: 2.7560x; 1.1852x over previous
//
#include <hip/hip_runtime.h>
#include <stdint.h>
#include <math.h>

typedef uint32_t u32;
typedef uint64_t u64;
typedef unsigned short u16;

#define B_T    16384
#define DD     512
#define NE     64
#define KCAP   512
#define TWO_D  1024

typedef __attribute__((ext_vector_type(8))) short bf16x8;
typedef __attribute__((ext_vector_type(4))) float f32x4;
typedef __attribute__((ext_vector_type(4))) u32 u32x4;

static __device__ __forceinline__ u32 mono_of(float s) {
  u32 b = __float_as_uint(s);
  return (b & 0x80000000u) ? ~b : (b | 0x80000000u);
}
static __device__ __forceinline__ float score_from_mono(u32 m) {
  u32 b = (m & 0x80000000u) ? (m ^ 0x80000000u) : ~m;
  return __uint_as_float(b);
}
static __device__ __forceinline__ u16 f2bf(float f) {
  u32 b = __float_as_uint(f);
  b += 0x7FFFu + ((b >> 16) & 1u);
  return (u16)(b >> 16);
}
static __device__ __forceinline__ u32 f2bf2(float lo, float hi) {
  return (u32)f2bf(lo) | ((u32)f2bf(hi) << 16);
}
static __device__ __forceinline__ float bf2f(u32 u) {
  return __uint_as_float(u << 16);
}
static __device__ __forceinline__ u32 cvtpk(float lo, float hi) {
  u32 r;
  asm("v_cvt_pk_bf16_f32 %0, %1, %2" : "=v"(r) : "v"(lo), "v"(hi));
  return r;
}
// async 16B global->LDS copy (dest: wave-uniform base + lane*16; src per-lane)
static __device__ __forceinline__ void gload_lds16(const u16* g, u16* l) {
  __builtin_amdgcn_global_load_lds(
      (const __attribute__((address_space(1))) u32*)(g),
      (__attribute__((address_space(3))) u32*)(l), 16, 0, 0);
}
static __device__ __forceinline__ bf16x8 negbf8(bf16x8 v) {
  u32x4 u;
  u32x4 s = *reinterpret_cast<u32x4*>(&v);
  u[0] = s[0] ^ 0x80008000u;
  u[1] = s[1] ^ 0x80008000u;
  u[2] = s[2] ^ 0x80008000u;
  u[3] = s[3] ^ 0x80008000u;
  return *reinterpret_cast<bf16x8*>(&u);
}

// ---------------------------------------------------------------- K0: x -> bf16 r/i split
__global__ __launch_bounds__(256) void k0_xconv(const float* __restrict__ x,
                                                u16* __restrict__ xrb,
                                                u16* __restrict__ xib) {
  int idx = blockIdx.x * 256 + threadIdx.x;
  float4 v = reinterpret_cast<const float4*>(x)[idx];
  reinterpret_cast<u32*>(xrb)[idx] = f2bf2(v.x, v.z);
  reinterpret_cast<u32*>(xib)[idx] = f2bf2(v.y, v.w);
}

// ---------------------------------------------------------------- K1: gate (FROZEN — exact)
__global__ __launch_bounds__(256) void k1_gate(const float* __restrict__ x,
                                               const float* __restrict__ gw,
                                               float* __restrict__ scoresT) {
  __shared__ __align__(16) float xs[128][64];
  __shared__ __align__(16) float gs[128][64];
  const int tb  = blockIdx.x * 64;
  const int tid = threadIdx.x;
  const int tx = tid & 15, ty = tid >> 4;

  float accC[4][4];
  float accT[4][4];
#pragma unroll
  for (int i = 0; i < 4; ++i)
#pragma unroll
    for (int j = 0; j < 4; ++j) { accC[i][j] = 0.f; accT[i][j] = 0.f; }

  for (int c = 0; c < 8; ++c) {
    const int k0 = c * 128;
    {
      const int t = tid & 63, ks = (tid >> 6) * 32;
      const float* src = x + (size_t)(tb + t) * TWO_D + k0 + ks;
#pragma unroll
      for (int i = 0; i < 8; ++i) {
        float4 v = reinterpret_cast<const float4*>(src)[i];
        xs[ks + i * 4 + 0][t] = v.x;
        xs[ks + i * 4 + 1][t] = v.y;
        xs[ks + i * 4 + 2][t] = v.z;
        xs[ks + i * 4 + 3][t] = v.w;
      }
      const float4* gsrc = reinterpret_cast<const float4*>(gw + (size_t)k0 * 64);
      float4* gdst = reinterpret_cast<float4*>(&gs[0][0]);
#pragma unroll
      for (int i = 0; i < 8; ++i) gdst[tid + i * 256] = gsrc[tid + i * 256];
    }
    __syncthreads();
    for (int k = 0; k < 128; ++k) {
      float4 a4 = *reinterpret_cast<float4*>(&xs[k][tx * 4]);
      float4 b4 = *reinterpret_cast<float4*>(&gs[k][ty * 4]);
      float av[4] = {a4.x, a4.y, a4.z, a4.w};
      float bv[4] = {b4.x, b4.y, b4.z, b4.w};
#pragma unroll
      for (int i = 0; i < 4; ++i)
#pragma unroll
        for (int j = 0; j < 4; ++j) accC[i][j] = fmaf(bv[i], av[j], accC[i][j]);
    }
    __syncthreads();
    if (c == 3 || c == 7) {
#pragma unroll
      for (int i = 0; i < 4; ++i)
#pragma unroll
        for (int j = 0; j < 4; ++j) {
          accT[i][j] = accT[i][j] + accC[i][j];
          accC[i][j] = 0.f;
        }
    }
  }
#pragma unroll
  for (int i = 0; i < 4; ++i) {
    float4 v = make_float4(accT[i][0], accT[i][1], accT[i][2], accT[i][3]);
    *reinterpret_cast<float4*>(&scoresT[(size_t)(ty * 4 + i) * B_T + tb + tx * 4]) = v;
  }
}

// ---------------------------------------------------------------- K2: top-k (rewritten, same output)
// 1024 threads; mono keys cached in LDS; rank-by-counting ordering
// (all selected u64 keys distinct => rank = #smaller). Fused invert.
__global__ __launch_bounds__(1024) void k2_topk(const float* __restrict__ scoresT,
                                                int* __restrict__ topk_idx,
                                                float* __restrict__ topk_scr,
                                                int* __restrict__ counts,
                                                int* __restrict__ entries) {
  const int e = blockIdx.x, tid = threadIdx.x;
  const float* row = scoresT + (size_t)e * B_T;
  __shared__ u32 keys[B_T];          // 64 KB
  __shared__ u32 hist[256];
  __shared__ u32 s_prefix, s_r;
  __shared__ u32 cnt_gt, cnt_eq;
  __shared__ u64 skey[512];
  __shared__ u32 tie[512];

  // load + monotonic-map whole row into LDS
#pragma unroll
  for (int i = 0; i < 4; ++i) {
    int v4 = i * 1024 + tid;
    float4 v = reinterpret_cast<const float4*>(row)[v4];
    keys[v4 * 4 + 0] = mono_of(v.x);
    keys[v4 * 4 + 1] = mono_of(v.y);
    keys[v4 * 4 + 2] = mono_of(v.z);
    keys[v4 * 4 + 3] = mono_of(v.w);
  }
  if (tid == 0) { s_prefix = 0; s_r = KCAP; cnt_gt = 0; cnt_eq = 0; }
  u32 prefmask = 0;
  __syncthreads();

  // 4-pass radix select on LDS keys
  for (int pass = 0; pass < 4; ++pass) {
    const int shift = 24 - 8 * pass;
    if (tid < 256) hist[tid] = 0;
    __syncthreads();
    const u32 prefix = s_prefix;
    for (int t = tid; t < B_T; t += 1024) {
      u32 m = keys[t];
      if ((m & prefmask) == prefix) atomicAdd(&hist[(m >> shift) & 0xFFu], 1u);
    }
    __syncthreads();
    if (tid == 0) {
      u32 r = s_r, cum = 0;
      int sel = 0;
      for (int b = 255; b >= 0; --b) {
        if (cum + hist[b] >= r) { sel = b; s_r = r - cum; break; }
        cum += hist[b];
      }
      s_prefix = prefix | ((u32)sel << shift);
    }
    prefmask |= (0xFFu << shift);
    __syncthreads();
  }

  const u32 kmono = s_prefix;
  const u32 rneed = s_r;

  // collect: strictly-greater into skey slots, ties into tie[]
  for (int t = tid; t < B_T; t += 1024) {
    u32 m = keys[t];
    if (m > kmono) {
      u32 p = atomicAdd(&cnt_gt, 1u);
      if (p < 512) skey[p] = ((u64)(~m) << 32) | (u32)t;
    } else if (m == kmono) {
      u32 p = atomicAdd(&cnt_eq, 1u);
      if (p < 512) tie[p] = (u32)t;
    }
  }
  __syncthreads();

  const u32 ngt = cnt_gt;
  const u32 ne = cnt_eq < 512u ? cnt_eq : 512u;
  // tie selection: rneed smallest indices, placed at ngt+rank (idx-ascending)
  if (tid < ne) {
    u32 my = tie[tid];
    u32 rank = 0;
    for (u32 j = 0; j < ne; ++j) rank += (tie[j] < my) ? 1u : 0u;
    if (rank < rneed) skey[ngt + rank] = ((u64)(~kmono) << 32) | my;
  }
  __syncthreads();

  // rank-order the 512 selected keys (distinct): rank = # smaller
  if (tid < 512) {
    u64 my = skey[tid];
    u32 rank = 0;
    for (int j = 0; j < 512; ++j) rank += (skey[j] < my) ? 1u : 0u;
    u32 idx = (u32)my;
    u32 m = ~((u32)(my >> 32));
    topk_idx[e * KCAP + rank] = (int)idx;
    topk_scr[e * KCAP + rank] = score_from_mono(m);
    // fused invert: y-row gid = rank*64 + e scatters to token idx
    int pos = atomicAdd(&counts[idx], 1);
    entries[idx * 64 + pos] = (int)(rank * 64 + e);
  }
}

// ---------------------------------------------------------------- K3: W -> bf16 transposed
__global__ __launch_bounds__(256) void k3_wtrans(const float* __restrict__ w,
                                                 u16* __restrict__ wrT,
                                                 u16* __restrict__ wiT) {
  __shared__ float2 tr[32][33];
  const int bid = blockIdx.x;
  const int e = bid >> 8, tile = bid & 255;
  const int d0 = (tile >> 4) * 32, f0 = (tile & 15) * 32;
  const int tid = threadIdx.x;
  const int fl2 = tid & 15, dl0 = tid >> 4;
  const float* base = w + ((size_t)e * 512 + d0) * 1024 + (size_t)f0 * 2;
#pragma unroll
  for (int it = 0; it < 2; ++it) {
    int dl = dl0 + it * 16;
    float4 v = *reinterpret_cast<const float4*>(base + (size_t)dl * 1024 + fl2 * 4);
    tr[dl][fl2 * 2]     = make_float2(v.x, v.y);
    tr[dl][fl2 * 2 + 1] = make_float2(v.z, v.w);
  }
  __syncthreads();
  const int d2 = (tid & 15) * 2, fl0 = tid >> 4;
#pragma unroll
  for (int it = 0; it < 2; ++it) {
    int f = fl0 + it * 16;
    float2 a = tr[d2][f], b = tr[d2 + 1][f];
    size_t off = ((size_t)e * 512 + f0 + f) * 512 + d0 + d2;
    *reinterpret_cast<u32*>(&wrT[off]) = f2bf2(a.x, b.x);
    *reinterpret_cast<u32*>(&wiT[off]) = f2bf2(a.y, b.y);
  }
}

// ---------------------------------------------------------------- K4: grouped complex GEMM
template <int PRECONV>
__global__ __launch_bounds__(256, 2) void k4_gemm(
    const float* __restrict__ x, const u16* __restrict__ xrb,
    const u16* __restrict__ xib, const int* __restrict__ topk_idx,
    const float* __restrict__ topk_scr, const u16* __restrict__ wrT,
    const u16* __restrict__ wiT, u16* __restrict__ yrw, u16* __restrict__ yiw) {
  const int bid = blockIdx.x;
  const int xcd = bid & 7, q = bid >> 3, t = q & 15, g = q >> 4;
  const int e = g * 8 + xcd;
  const int mb = t & 3, fb = t >> 2;
  const int m0 = mb * 128, f0 = fb * 128;

  __shared__ __align__(16) u16 Ar[4096];
  __shared__ __align__(16) u16 Ai[4096];
  __shared__ __align__(16) u16 Bu[4096];
  __shared__ __align__(16) u16 Bv[4096];
  __shared__ int tok[128];
  __shared__ float scr[128];

  const int tid = threadIdx.x;
  if (tid < 128) {
    tok[tid] = topk_idx[e * KCAP + m0 + tid];
    scr[tid] = topk_scr[e * KCAP + m0 + tid];
  }
  __syncthreads();

  const int r0  = tid & 127;
  const int ka0 = (tid >> 7) * 8;
  const int ka1 = ka0 + 16;
  const size_t brow = ((size_t)e * 512 + f0 + r0) * 512;
  const int wv = tid >> 6, ln = tid & 63;
  const int d0 = wv * 512;
  const int d1 = 2048 + wv * 512;

  const int mytok = tok[r0];
  const size_t arow_bf = (size_t)mytok * 512;
  const int row = tid >> 1, half = tid & 1;
  const float* arow_f = x + (size_t)tok[row] * TWO_D + half * 32;

  const int mbase = (wv >> 1) * 64, nbase = (wv & 1) * 64;
  const int frow = ln & 15, fq = ln >> 4;
  const int ra = fq * 1024 + (mbase + frow) * 8;
  const int rb = fq * 1024 + (nbase + frow) * 8;

  f32x4 accR[4][4] = {};
  f32x4 accI[4][4] = {};

  for (int step = 0; step < 16; ++step) {
    const int k0 = step * 32;
    gload_lds16(wrT + brow + k0 + ka0, Bu + d0);
    gload_lds16(wrT + brow + k0 + ka1, Bu + d1);
    gload_lds16(wiT + brow + k0 + ka0, Bv + d0);
    gload_lds16(wiT + brow + k0 + ka1, Bv + d1);
    if (PRECONV) {
      gload_lds16(xrb + arow_bf + k0 + ka0, Ar + d0);
      gload_lds16(xrb + arow_bf + k0 + ka1, Ar + d1);
      gload_lds16(xib + arow_bf + k0 + ka0, Ai + d0);
      gload_lds16(xib + arow_bf + k0 + ka1, Ai + d1);
    } else {
      const float4* ap = reinterpret_cast<const float4*>(arow_f + (size_t)k0 * 2);
      u32 xr[8], xi[8];
#pragma unroll
      for (int i = 0; i < 8; ++i) {
        float4 v = ap[i];
        xr[i] = cvtpk(v.x, v.z);
        xi[i] = cvtpk(v.y, v.w);
      }
      uint4 wa, wb;
      wa.x = xr[0]; wa.y = xr[1]; wa.z = xr[2]; wa.w = xr[3];
      wb.x = xr[4]; wb.y = xr[5]; wb.z = xr[6]; wb.w = xr[7];
      *reinterpret_cast<uint4*>(&Ar[(2 * half) * 1024 + row * 8]) = wa;
      *reinterpret_cast<uint4*>(&Ar[(2 * half + 1) * 1024 + row * 8]) = wb;
      wa.x = xi[0]; wa.y = xi[1]; wa.z = xi[2]; wa.w = xi[3];
      wb.x = xi[4]; wb.y = xi[5]; wb.z = xi[6]; wb.w = xi[7];
      *reinterpret_cast<uint4*>(&Ai[(2 * half) * 1024 + row * 8]) = wa;
      *reinterpret_cast<uint4*>(&Ai[(2 * half + 1) * 1024 + row * 8]) = wb;
    }
    __syncthreads();

    bf16x8 ar[4], ai[4], bu[4], bv[4];
#pragma unroll
    for (int m = 0; m < 4; ++m) {
      ar[m] = *reinterpret_cast<const bf16x8*>(&Ar[ra + m * 128]);
      ai[m] = *reinterpret_cast<const bf16x8*>(&Ai[ra + m * 128]);
    }
#pragma unroll
    for (int n = 0; n < 4; ++n) {
      bu[n] = *reinterpret_cast<const bf16x8*>(&Bu[rb + n * 128]);
      bv[n] = *reinterpret_cast<const bf16x8*>(&Bv[rb + n * 128]);
    }
#pragma unroll
    for (int m = 0; m < 4; ++m)
#pragma unroll
      for (int n = 0; n < 4; ++n) {
        bf16x8 bw = negbf8(bv[n]);
        accR[m][n] = __builtin_amdgcn_mfma_f32_16x16x32_bf16(ar[m], bu[n], accR[m][n], 0, 0, 0);
        accR[m][n] = __builtin_amdgcn_mfma_f32_16x16x32_bf16(ai[m], bw,    accR[m][n], 0, 0, 0);
        accI[m][n] = __builtin_amdgcn_mfma_f32_16x16x32_bf16(ar[m], bv[n], accI[m][n], 0, 0, 0);
        accI[m][n] = __builtin_amdgcn_mfma_f32_16x16x32_bf16(ai[m], bu[n], accI[m][n], 0, 0, 0);
      }
    __syncthreads();
  }

  const int rr = fq * 4;
#pragma unroll
  for (int m = 0; m < 4; ++m) {
#pragma unroll
    for (int r = 0; r < 4; ++r) {
      const int jl = mbase + m * 16 + rr + r;
      const float ww = scr[jl];
      const size_t ybase = ((size_t)e * KCAP + m0 + jl) * DD;
#pragma unroll
      for (int n = 0; n < 4; ++n) {
        const int fg = f0 + nbase + n * 16 + frow;
        yrw[ybase + fg] = f2bf(accR[m][n][r] * ww);
        yiw[ybase + fg] = f2bf(accI[m][n][r] * ww);
      }
    }
  }
}

// ---------------------------------------------------------------- K5: gather + GELU
#define GELU(z) (0.5f * (z) * (1.0f + erff((z)*0.70710678118654752440f)))
__global__ __launch_bounds__(256) void k5_gather(
    const u16* __restrict__ yrw, const u16* __restrict__ yiw,
    const int* __restrict__ counts, const int* __restrict__ entries,
    const float* __restrict__ bias, float* __restrict__ out) {
  const int t = blockIdx.x;
  const int tid = threadIdx.x;
  const int c = counts[t];
  const float inv = 1.0f / (float)(c > 0 ? c : 1);
  const int f0 = tid * 2;
  float sr0 = 0.f, sr1 = 0.f, si0 = 0.f, si1 = 0.f;
  for (int i = 0; i < c; ++i) {
    int srcrow = entries[t * 64 + i];
    size_t off = (size_t)srcrow * DD + f0;
    u32 pr = *reinterpret_cast<const u32*>(yrw + off);
    u32 pi = *reinterpret_cast<const u32*>(yiw + off);
    sr0 += bf2f(pr & 0xFFFFu); sr1 += bf2f(pr >> 16);
    si0 += bf2f(pi & 0xFFFFu); si1 += bf2f(pi >> 16);
  }
  const float b0 = bias[f0], b1 = bias[f0 + 1];
  float v0 = sr0 * inv + b0;
  float v1 = si0 * inv + b0;
  float v2 = sr1 * inv + b1;
  float v3 = si1 * inv + b1;
  float4 o = make_float4(GELU(v0), GELU(v1), GELU(v2), GELU(v3));
  *reinterpret_cast<float4*>(&out[(size_t)t * TWO_D + f0 * 2]) = o;
}

// ---------------------------------------------------------------- launch
extern "C" void kernel_launch(void* const* d_in, const int* in_sizes, int n_in,
                              void* d_out, int out_size, void* d_ws, size_t ws_size,
                              hipStream_t stream) {
  const float* x    = (const float*)d_in[0];
  const float* gw   = (const float*)d_in[1];
  const float* w    = (const float*)d_in[2];
  const float* bias = (const float*)d_in[3];
  float* out = (float*)d_out;

  char* ws = (char*)d_ws;
  u16*   yrw     = (u16*)(ws);                  //  32 MiB (aliases scoresT)
  float* scoresT = (float*)(ws);                //   4 MiB (dead before k4)
  u16*   yiw     = (u16*)(ws + 33554432);       //  32 MiB
  int*   tidx    = (int*)(ws + 67108864);       //  128 KiB
  float* tscr    = (float*)(ws + 67239936);     //  128 KiB
  int*   counts  = (int*)(ws + 67371008);       //  64 KiB
  int*   entries = (int*)(ws + 67436544);       //   4 MiB
  u16*   wrT     = (u16*)(ws + 71630848);       //  32 MiB
  u16*   wiT     = (u16*)(ws + 105185280);      //  32 MiB  (end: 138,739,712)
  u16*   xrb     = (u16*)(ws + 138739712);      //  16 MiB  (preconv only)
  u16*   xib     = (u16*)(ws + 155516928);      //  16 MiB  (end: 172,294,144)

  const bool preconv = ws_size >= 172294144ull;

  hipMemsetAsync(counts, 0, B_T * sizeof(int), stream);
  k1_gate<<<B_T / 64, 256, 0, stream>>>(x, gw, scoresT);
  k2_topk<<<NE, 1024, 0, stream>>>(scoresT, tidx, tscr, counts, entries);
  k3_wtrans<<<NE * 256, 256, 0, stream>>>(w, wrT, wiT);
  if (preconv) {
    k0_xconv<<<16384, 256, 0, stream>>>(x, xrb, xib);
    k4_gemm<1><<<1024, 256, 0, stream>>>(x, xrb, xib, tidx, tscr, wrT, wiT, yrw, yiw);
  } else {
    k4_gemm<0><<<1024, 256, 0, stream>>>(x, nullptr, nullptr, tidx, tscr, wrT, wiT, yrw, yiw);
  }
  k5_gather<<<B_T, 256, 0, stream>>>(yrw, yiw, counts, entries, bias, out);
}